// Round 6
// baseline (555.311 us; speedup 1.0000x reference)
//
#include <hip/hip_runtime.h>
#include <hip/hip_cooperative_groups.h>

#define NE 8
#define CAP 1024
#define HD 1024
#define ID 1408
#define TT 2048

typedef __attribute__((ext_vector_type(8))) short bf16x8;
typedef __attribute__((ext_vector_type(4))) float f32x4;
typedef unsigned short u16;
typedef unsigned int u32;
typedef unsigned long long u64;

__device__ __forceinline__ u16 f2bf(float f) {
  u32 u = __float_as_uint(f);
  u = (u + 0x7fffu + ((u >> 16) & 1u)) >> 16;
  return (u16)u;
}

__device__ __forceinline__ bf16x8 pack8(float4 a, float4 b) {
  bf16x8 r;
  r[0] = (short)f2bf(a.x); r[1] = (short)f2bf(a.y);
  r[2] = (short)f2bf(a.z); r[3] = (short)f2bf(a.w);
  r[4] = (short)f2bf(b.x); r[5] = (short)f2bf(b.y);
  r[6] = (short)f2bf(b.z); r[7] = (short)f2bf(b.w);
  return r;
}

__device__ __forceinline__ void async_cp16(const void* g, void* l) {
  __builtin_amdgcn_global_load_lds(
      (const __attribute__((address_space(1))) u32*)g,
      (__attribute__((address_space(3))) u32*)l, 16, 0, 0);
}

#define W1U (NE * 2 * ID)                           // 22528 w1-row cvt units
#define XU (TT * HD / 1024)                         // 2048 x cvt units
#define PTOT (W1U + XU)                             // 24576
#define G1TILES (NE * (CAP / 64) * (2 * ID / 128))  // 2816
#define G1TOT (768 + G1TILES)                       // riders + tiles
#define G2TILES (NE * (CAP / 64) * (HD / 64))       // 2048
#define G1BUF 24576
#define G2BUF 16384

#define STAGE1(base, kt)                                             \
  do {                                                               \
    int ko_ = (kt) * 64;                                             \
    char* sb_ = (base);                                              \
    async_cp16(aP[0] + ko_, sb_ + (0 * 256 + tid) * 16);             \
    async_cp16(aP[1] + ko_, sb_ + (1 * 256 + tid) * 16);             \
    async_cp16(bP[0] + ko_, sb_ + 8192 + (0 * 256 + tid) * 16);      \
    async_cp16(bP[1] + ko_, sb_ + 8192 + (1 * 256 + tid) * 16);      \
    async_cp16(bP[2] + ko_, sb_ + 8192 + (2 * 256 + tid) * 16);      \
    async_cp16(bP[3] + ko_, sb_ + 8192 + (3 * 256 + tid) * 16);      \
  } while (0)

#define STAGE2(base, kt)                                             \
  do {                                                               \
    int ko_ = (kt) * 64;                                             \
    char* sb_ = (base);                                              \
    async_cp16(aP[0] + ko_, sb_ + (0 * 256 + tid) * 16);             \
    async_cp16(aP[1] + ko_, sb_ + (1 * 256 + tid) * 16);             \
    async_cp16(bP[0] + ko_, sb_ + 8192 + (0 * 256 + tid) * 16);      \
    async_cp16(bP[1] + ko_, sb_ + 8192 + (1 * 256 + tid) * 16);      \
  } while (0)

// One cooperative launch: phase0 (route + w1/x cvt) | sync | phase1 (w2-cvt
// riders + out-zero riders + gemm1 64x128 depth-2 counted-vmcnt tiles) | sync
// | phase2 (gemm2 64x64 tiles + atomic combine). phase==-1: all, with
// grid.sync. phase>=0: that phase only (classic-launch fallback path).
__global__ __launch_bounds__(256, 2) void mega_kernel(
    const float4* __restrict__ x32, const float4* __restrict__ w1,
    const float4* __restrict__ w2, const float* __restrict__ tw,
    const int* __restrict__ ids, float* __restrict__ out,
    ushort4* __restrict__ bw1, bf16x8* __restrict__ bw2,
    ushort4* __restrict__ bx, u16* __restrict__ hbuf,
    int* __restrict__ rowmap, int* __restrict__ counts, int phase) {
  __shared__ __align__(16) char sm[3 * G1BUF];  // 72 KB -> 2 blocks/CU
  int bid = blockIdx.x, nb = gridDim.x, tid = threadIdx.x;

  // ======================= phase 0: route + cvt streams ======================
  if (phase == -1 || phase == 0) {
    if (bid == 0) {
      unsigned char* ids_s = (unsigned char*)sm;       // 4 KB
      int(*sc)[NE + 1] = (int(*)[NE + 1])(sm + 4096);  // 9 KB
      for (int i = tid; i < TT * 2; i += 256) ids_s[i] = (unsigned char)ids[i];
      __syncthreads();
      int base = tid * 16;
      u64 own64 = 0;
#pragma unroll
      for (int j = 0; j < 16; ++j) own64 += 1ull << (ids_s[base + j] * 8);
      int own[NE];
#pragma unroll
      for (int e = 0; e < NE; ++e) {
        own[e] = (int)((own64 >> (e * 8)) & 0xff);
        sc[tid][e] = own[e];
      }
      __syncthreads();
      for (int off = 1; off < 256; off <<= 1) {
        int v[NE];
        if (tid >= off) {
#pragma unroll
          for (int e = 0; e < NE; ++e) v[e] = sc[tid - off][e];
        }
        __syncthreads();
        if (tid >= off) {
#pragma unroll
          for (int e = 0; e < NE; ++e) sc[tid][e] += v[e];
        }
        __syncthreads();
      }
      if (tid == 255) {
#pragma unroll
        for (int e = 0; e < NE; ++e) counts[e] = sc[255][e] < CAP ? sc[255][e] : CAP;
      }
      int excl[NE];
#pragma unroll
      for (int e = 0; e < NE; ++e) excl[e] = sc[tid][e] - own[e];
      __syncthreads();
#pragma unroll
      for (int e = 0; e < NE; ++e) sc[tid][e] = excl[e];
#pragma unroll
      for (int j = 0; j < 16; ++j) {
        int f = base + j;
        int e = ids_s[f];
        int p = sc[tid][e]++;
        if (p < CAP) rowmap[e * CAP + p] = f;
      }
      __syncthreads();  // sm reused by phase 1
    } else {
      // streaming cvt, 4-deep batches (8 waves/CU needs >=4 loads in flight)
      int stride = nb - 1;
      for (int u0 = bid - 1; u0 < PTOT; u0 += 4 * stride) {
        float4 v[4];
        ushort4* dp[4];
        bool ok[4];
#pragma unroll
        for (int k = 0; k < 4; ++k) {
          int u = u0 + k * stride;
          ok[k] = (u < PTOT);
          if (ok[k]) {
            const float4* sp;
            ushort4* dd;
            if (u < W1U) {
              int e = u / (2 * ID);
              int n = u - e * (2 * ID);
              int jj = (n < ID) ? n : (n - ID);
              int np = (jj >> 4) * 32 + (jj & 15) + ((n < ID) ? 0 : 16);
              sp = w1 + ((size_t)e * (2 * ID) + n) * (HD / 4);
              dd = bw1 + ((size_t)e * (2 * ID) + np) * (HD / 4);
            } else {
              int xi = u - W1U;
              sp = x32 + (size_t)xi * 256;
              dd = bx + (size_t)xi * 256;
            }
            v[k] = sp[tid];
            dp[k] = dd + tid;
          }
        }
#pragma unroll
        for (int k = 0; k < 4; ++k)
          if (ok[k]) {
            ushort4 o;
            o.x = f2bf(v[k].x); o.y = f2bf(v[k].y);
            o.z = f2bf(v[k].z); o.w = f2bf(v[k].w);
            *dp[k] = o;
          }
      }
    }
  }
  if (phase == -1) {
    __threadfence();
    cooperative_groups::this_grid().sync();
  }

  // ====== phase 1: w2-cvt riders | out-zero riders | gemm1 64x128 tiles ======
  if (phase == -1 || phase == 1) {
    for (int idx = bid; idx < G1TOT; idx += nb) {
      if (idx < 704) {  // w2 cvt riders: 704 x 4 x 16KB
#pragma unroll
        for (int k2 = 0; k2 < 4; ++k2) {
          size_t base4 = ((size_t)idx * 4 + k2) * 1024;
          float4 v0 = w2[base4 + tid * 2];
          float4 v1 = w2[base4 + tid * 2 + 1];
          float4 v2 = w2[base4 + 512 + tid * 2];
          float4 v3 = w2[base4 + 512 + tid * 2 + 1];
          bf16x8* dst = bw2 + base4 / 2;
          dst[tid] = pack8(v0, v1);
          dst[256 + tid] = pack8(v2, v3);
        }
        continue;
      }
      if (idx < 768) {  // out-zero riders: 64 x 8192 float4
        size_t base = (size_t)(idx - 704) * 8192;
        float4 z = {0.f, 0.f, 0.f, 0.f};
        float4* o4 = (float4*)out;
#pragma unroll
        for (int i2 = 0; i2 < 32; ++i2) o4[base + i2 * 256 + tid] = z;
        continue;
      }
      int g = idx - 768;
      int e = g & 7;
      int m0 = ((g >> 3) & 15) * 64;
      int n0 = (g >> 7) * 128;
      int count = counts[e];
      if (m0 >= count) continue;
      int lane = tid & 63, wid = tid >> 6;
      int wm = wid >> 1, wn = wid & 1;
      int q = lane >> 4, lm = lane & 15;
      int rloc = tid >> 3;
      int chs = ((tid & 7) ^ (rloc & 7)) * 8;
      const u16* A = (const u16*)bx;
      const u16* B = (const u16*)bw1;
      const u16* aP[2];
      const u16* bP[4];
#pragma unroll
      for (int i = 0; i < 2; ++i) {
        int gr = m0 + rloc + 32 * i;
        int f = (gr < count) ? rowmap[e * CAP + gr] : 0;
        aP[i] = A + (size_t)(f >> 1) * HD + chs;
      }
#pragma unroll
      for (int i = 0; i < 4; ++i)
        bP[i] = B + ((size_t)e * 2 * ID + n0 + rloc + 32 * i) * HD + chs;

      f32x4 zero = {0.f, 0.f, 0.f, 0.f};
      f32x4 acc[2][4];
#pragma unroll
      for (int mi = 0; mi < 2; ++mi)
#pragma unroll
        for (int ni = 0; ni < 4; ++ni) acc[mi][ni] = zero;

      STAGE1(sm, 0);
      STAGE1(sm + G1BUF, 1);
      int p = 0, pn2 = 2;
      for (int kt = 0; kt < HD / 64; ++kt) {
        if (kt == HD / 64 - 1)
          asm volatile("s_waitcnt vmcnt(0)\ns_barrier" ::: "memory");
        else
          asm volatile("s_waitcnt vmcnt(6)\ns_barrier" ::: "memory");
        const char* sb = sm + p * G1BUF;
        if (kt + 2 < HD / 64) STAGE1(sm + pn2 * G1BUF, kt + 2);
#pragma unroll
        for (int s = 0; s < 2; ++s) {
          int cs = ((s * 4 + q) ^ (lm & 7)) * 16;
          bf16x8 af[2], bfr[4];
#pragma unroll
          for (int mi = 0; mi < 2; ++mi)
            af[mi] = *(const bf16x8*)(sb + (wm * 32 + mi * 16 + lm) * 128 + cs);
#pragma unroll
          for (int ni = 0; ni < 4; ++ni)
            bfr[ni] = *(const bf16x8*)(sb + 8192 + (wn * 64 + ni * 16 + lm) * 128 + cs);
          __builtin_amdgcn_s_setprio(1);
#pragma unroll
          for (int mi = 0; mi < 2; ++mi)
#pragma unroll
            for (int ni = 0; ni < 4; ++ni)
              acc[mi][ni] = __builtin_amdgcn_mfma_f32_16x16x32_bf16(af[mi], bfr[ni], acc[mi][ni], 0, 0, 0);
          __builtin_amdgcn_s_setprio(0);
        }
        p = (p == 2) ? 0 : p + 1;
        pn2 = (pn2 == 2) ? 0 : pn2 + 1;
      }
      __syncthreads();

      u16* smOut = (u16*)sm;  // [64][72]
#pragma unroll
      for (int mi = 0; mi < 2; ++mi) {
#pragma unroll
        for (int k = 0; k < 2; ++k) {
          int colL = wn * 32 + k * 16 + lm;
#pragma unroll
          for (int r = 0; r < 4; ++r) {
            float g2 = acc[mi][2 * k][r];
            float u = acc[mi][2 * k + 1][r];
            float a = g2 / (1.f + __expf(-g2)) * u;
            int row = wm * 32 + mi * 16 + q * 4 + r;
            smOut[row * 72 + colL] = f2bf(a);
          }
        }
      }
      __syncthreads();
      {
        int row = tid >> 2, seg = tid & 3;
        const u16* sp = smOut + row * 72 + seg * 16;
        bf16x8 v0 = *(const bf16x8*)sp;
        bf16x8 v1 = *(const bf16x8*)(sp + 8);
        u16* dp = hbuf + ((size_t)e * CAP + m0 + row) * ID + (n0 >> 1) + seg * 16;
        *(bf16x8*)dp = v0;
        *(bf16x8*)(dp + 8) = v1;
      }
      __syncthreads();  // sm safe for next unit
    }
  }
  if (phase == -1) {
    __threadfence();
    cooperative_groups::this_grid().sync();
  }

  // ================ phase 2: gemm2 64x64 tiles + atomic combine ==============
  if (phase == -1 || phase == 2) {
    for (int idx = bid; idx < G2TILES; idx += nb) {
      int e = idx & 7;
      int m0 = ((idx >> 3) & 15) * 64;
      int n0 = (idx >> 7) * 64;
      int count = counts[e];
      if (m0 >= count) continue;
      int lane = tid & 63, wid = tid >> 6;
      int wm = wid >> 1, wn = wid & 1;
      int q = lane >> 4, lm = lane & 15;
      int rloc = tid >> 3;
      int chs = ((tid & 7) ^ (rloc & 7)) * 8;
      const u16* A = hbuf;
      const u16* B = (const u16*)bw2;
      const u16* aP[2];
      const u16* bP[2];
#pragma unroll
      for (int i = 0; i < 2; ++i) {
        aP[i] = A + ((size_t)e * CAP + m0 + rloc + 32 * i) * ID + chs;
        bP[i] = B + ((size_t)e * HD + n0 + rloc + 32 * i) * ID + chs;
      }

      f32x4 zero = {0.f, 0.f, 0.f, 0.f};
      f32x4 acc[2][2];
#pragma unroll
      for (int mi = 0; mi < 2; ++mi)
#pragma unroll
        for (int ni = 0; ni < 2; ++ni) acc[mi][ni] = zero;

      STAGE2(sm, 0);
      STAGE2(sm + G2BUF, 1);
      int p = 0, pn2 = 2;
      for (int kt = 0; kt < ID / 64; ++kt) {
        if (kt == ID / 64 - 1)
          asm volatile("s_waitcnt vmcnt(0)\ns_barrier" ::: "memory");
        else
          asm volatile("s_waitcnt vmcnt(4)\ns_barrier" ::: "memory");
        const char* sb = sm + p * G2BUF;
        if (kt + 2 < ID / 64) STAGE2(sm + pn2 * G2BUF, kt + 2);
#pragma unroll
        for (int s = 0; s < 2; ++s) {
          int cs = ((s * 4 + q) ^ (lm & 7)) * 16;
          bf16x8 af[2], bfr[2];
#pragma unroll
          for (int mi = 0; mi < 2; ++mi)
            af[mi] = *(const bf16x8*)(sb + (wm * 32 + mi * 16 + lm) * 128 + cs);
#pragma unroll
          for (int ni = 0; ni < 2; ++ni)
            bfr[ni] = *(const bf16x8*)(sb + 8192 + (wn * 32 + ni * 16 + lm) * 128 + cs);
          __builtin_amdgcn_s_setprio(1);
#pragma unroll
          for (int mi = 0; mi < 2; ++mi)
#pragma unroll
            for (int ni = 0; ni < 2; ++ni)
              acc[mi][ni] = __builtin_amdgcn_mfma_f32_16x16x32_bf16(af[mi], bfr[ni], acc[mi][ni], 0, 0, 0);
          __builtin_amdgcn_s_setprio(0);
        }
        p = (p == 2) ? 0 : p + 1;
        pn2 = (pn2 == 2) ? 0 : pn2 + 1;
      }

#pragma unroll
      for (int mi = 0; mi < 2; ++mi) {
#pragma unroll
        for (int r = 0; r < 4; ++r) {
          int grow = m0 + wm * 32 + mi * 16 + q * 4 + r;
          if (grow < count) {
            int f = rowmap[e * CAP + grow];
            float w = tw[f];
            int t = f >> 1;
#pragma unroll
            for (int ni = 0; ni < 2; ++ni) {
              int col = n0 + wn * 32 + ni * 16 + lm;
              atomicAdd(&out[(size_t)t * HD + col], w * acc[mi][ni][r]);
            }
          }
        }
      }
      __syncthreads();  // sm safe for next unit
    }
  }
}

extern "C" void kernel_launch(void* const* d_in, const int* in_sizes, int n_in,
                              void* d_out, int out_size, void* d_ws, size_t ws_size,
                              hipStream_t stream) {
  const float4* x32 = (const float4*)d_in[0];
  const float4* w1 = (const float4*)d_in[1];
  const float4* w2 = (const float4*)d_in[2];
  const float* tw = (const float*)d_in[3];
  const int* ids = (const int*)d_in[4];
  float* out = (float*)d_out;

  char* p = (char*)d_ws;
  auto alloc = [&](size_t b) { char* r = p; p += (b + 255) & ~(size_t)255; return r; };
  ushort4* bw1 = (ushort4*)alloc((size_t)NE * 2 * ID * HD * 2);  // 46.1 MB
  bf16x8* bw2 = (bf16x8*)alloc((size_t)NE * HD * ID * 2);        // 23.1 MB
  ushort4* bx = (ushort4*)alloc((size_t)TT * HD * 2);            // 4.2 MB
  u16* hbuf = (u16*)alloc((size_t)NE * CAP * ID * 2);            // 23.1 MB
  int* rowmap = (int*)alloc((size_t)NE * CAP * 4);
  int* counts = (int*)alloc((size_t)NE * 4);

  static int gblk = 0;
  if (gblk == 0) {
    int nbmax = 0;
    hipOccupancyMaxActiveBlocksPerMultiprocessor(&nbmax, mega_kernel, 256, 0);
    if (nbmax < 1) nbmax = 1;
    gblk = nbmax * 256;  // 256 CUs on MI355X
    if (gblk > 512) gblk = 512;
  }

  int ph = -1;
  void* args[] = {&x32, &w1, &w2, &tw, &ids, &out, &bw1, &bw2,
                  &bx,  &hbuf, &rowmap, &counts, &ph};
  hipError_t err = hipLaunchCooperativeKernel(
      mega_kernel, dim3(gblk), dim3(256), args, 0, stream);
  if (err != hipSuccess) {
    // fallback: same kernel, classic 3-launch (no grid.sync on this path)
    mega_kernel<<<512, 256, 0, stream>>>(x32, w1, w2, tw, ids, out, bw1, bw2,
                                         bx, hbuf, rowmap, counts, 0);
    mega_kernel<<<512, 256, 0, stream>>>(x32, w1, w2, tw, ids, out, bw1, bw2,
                                         bx, hbuf, rowmap, counts, 1);
    mega_kernel<<<512, 256, 0, stream>>>(x32, w1, w2, tw, ids, out, bw1, bw2,
                                         bx, hbuf, rowmap, counts, 2);
  }
}

// Round 7
// 250.611 us; speedup vs baseline: 2.2158x; 2.2158x over previous
//
#include <hip/hip_runtime.h>

#define NE 8
#define CAP 1024
#define HD 1024
#define ID 1408
#define TT 2048

typedef __attribute__((ext_vector_type(8))) short bf16x8;
typedef __attribute__((ext_vector_type(4))) float f32x4;
typedef unsigned short u16;
typedef unsigned int u32;
typedef unsigned long long u64;

__device__ __forceinline__ u16 f2bf(float f) {
  u32 u = __float_as_uint(f);
  u = (u + 0x7fffu + ((u >> 16) & 1u)) >> 16;
  return (u16)u;
}

__device__ __forceinline__ bf16x8 pack8(float4 a, float4 b) {
  bf16x8 r;
  r[0] = (short)f2bf(a.x); r[1] = (short)f2bf(a.y);
  r[2] = (short)f2bf(a.z); r[3] = (short)f2bf(a.w);
  r[4] = (short)f2bf(b.x); r[5] = (short)f2bf(b.y);
  r[6] = (short)f2bf(b.z); r[7] = (short)f2bf(b.w);
  return r;
}

__device__ __forceinline__ void async_cp16(const void* g, void* l) {
  __builtin_amdgcn_global_load_lds(
      (const __attribute__((address_space(1))) u32*)g,
      (__attribute__((address_space(3))) u32*)l, 16, 0, 0);
}

// ---------------- prep: route (block 0) + w1 il-cvt + x cvt + out zero -------
// r0-proven small-block streaming form (1 float4/thread).
#define W1ROWS (NE * 2 * ID)       // 22528 blocks, one per (row,expert)
#define XBLK (TT * HD / 4 / 256)   // 2048 blocks
#define OZB (TT * HD / 4 / 256)    // 2048 blocks (out zero, moved from riders)
__global__ __launch_bounds__(256) void prep_kernel(
    const float4* __restrict__ w1, ushort4* __restrict__ bw1,
    const float4* __restrict__ x, ushort4* __restrict__ bx,
    const int* __restrict__ ids, int* __restrict__ rowmap,
    int* __restrict__ counts, float4* __restrict__ outz) {
  int b = blockIdx.x;
  int tid = threadIdx.x;
  if (b == 0) {
    // ---- routing: exact flat-order cumsum positions ----
    __shared__ unsigned char ids_s[TT * 2];
    __shared__ int sc[256][NE + 1];
    for (int i = tid; i < TT * 2; i += 256) ids_s[i] = (unsigned char)ids[i];
    __syncthreads();
    int base = tid * 16;
    u64 own64 = 0;
#pragma unroll
    for (int j = 0; j < 16; ++j) own64 += 1ull << (ids_s[base + j] * 8);
    int own[NE];
#pragma unroll
    for (int e = 0; e < NE; ++e) {
      own[e] = (int)((own64 >> (e * 8)) & 0xff);
      sc[tid][e] = own[e];
    }
    __syncthreads();
    for (int off = 1; off < 256; off <<= 1) {
      int v[NE];
      if (tid >= off) {
#pragma unroll
        for (int e = 0; e < NE; ++e) v[e] = sc[tid - off][e];
      }
      __syncthreads();
      if (tid >= off) {
#pragma unroll
        for (int e = 0; e < NE; ++e) sc[tid][e] += v[e];
      }
      __syncthreads();
    }
    if (tid == 255) {
#pragma unroll
      for (int e = 0; e < NE; ++e) counts[e] = sc[255][e] < CAP ? sc[255][e] : CAP;
    }
    int excl[NE];
#pragma unroll
    for (int e = 0; e < NE; ++e) excl[e] = sc[tid][e] - own[e];
    __syncthreads();
#pragma unroll
    for (int e = 0; e < NE; ++e) sc[tid][e] = excl[e];
#pragma unroll
    for (int j = 0; j < 16; ++j) {
      int f = base + j;
      int e = ids_s[f];
      int p = sc[tid][e]++;
      if (p < CAP) rowmap[e * CAP + p] = f;
    }
    return;
  }
  int bb = b - 1;
  if (bb < W1ROWS) {
    // w1 interleave-cvt: gate j -> (j>>4)*32+(j&15), up -> +16
    int n = bb % (2 * ID);
    int e = bb / (2 * ID);
    int j = (n < ID) ? n : (n - ID);
    int np = (j >> 4) * 32 + (j & 15) + ((n < ID) ? 0 : 16);
    float4 v = w1[((size_t)e * 2 * ID + n) * (HD / 4) + tid];
    ushort4 o;
    o.x = f2bf(v.x); o.y = f2bf(v.y); o.z = f2bf(v.z); o.w = f2bf(v.w);
    bw1[((size_t)e * 2 * ID + np) * (HD / 4) + tid] = o;
  } else if (bb < W1ROWS + XBLK) {
    size_t i = (size_t)(bb - W1ROWS) * 256 + tid;
    float4 v = x[i];
    ushort4 o;
    o.x = f2bf(v.x); o.y = f2bf(v.y); o.z = f2bf(v.z); o.w = f2bf(v.w);
    bx[i] = o;
  } else {
    size_t i = (size_t)(bb - W1ROWS - XBLK) * 256 + tid;
    float4 z = {0.f, 0.f, 0.f, 0.f};
    outz[i] = z;
  }
}

// ---------------- GEMM1 (+ interleaved riders): 64x128, depth-2 pipeline -----
// Grid = 308 groups x 8 blocks = 2464. Per 7 groups: 5 tile-groups, 2 w2-cvt
// rider-groups (r7==2,5) -> riders' BW work co-schedules with tile MFMA across
// the whole kernel (m114) instead of front-serializing. e = bid&7 everywhere,
// preserving r5's expert->XCD L2 affinity (FETCH stayed ~49MB). Tile y-dim
// trimmed 16->10 with m0+=640 loop (counts~512 -> ~45% fewer dead blocks).
#define G1BUF 24576
__global__ __launch_bounds__(256) void gemm1_kernel(
    const u16* __restrict__ A, const u16* __restrict__ B, u16* __restrict__ Hb,
    const int* __restrict__ rowmap, const int* __restrict__ counts,
    const float4* __restrict__ W2, bf16x8* __restrict__ bw2) {
  int bid = blockIdx.x;
  int tid = threadIdx.x;
  int grp = bid >> 3, sub = bid & 7;
  int q7 = grp / 7, r7 = grp - q7 * 7;
  if (r7 == 2 || r7 == 5) {  // ---- w2 cvt rider: 88 groups x 8 = 704 ----
    int r = (q7 * 2 + (r7 == 5 ? 1 : 0)) * 8 + sub;
#pragma unroll
    for (int k2 = 0; k2 < 4; ++k2) {
      size_t base4 = ((size_t)r * 4 + k2) * 1024;
      float4 v0 = W2[base4 + tid * 2];
      float4 v1 = W2[base4 + tid * 2 + 1];
      float4 v2 = W2[base4 + 512 + tid * 2];
      float4 v3 = W2[base4 + 512 + tid * 2 + 1];
      bf16x8* dst = bw2 + base4 / 2;
      dst[tid] = pack8(v0, v1);
      dst[256 + tid] = pack8(v2, v3);
    }
    return;
  }
  int tg = q7 * 5 + r7 - (r7 > 2 ? 1 : 0) - (r7 > 5 ? 1 : 0);  // 0..219
  int e = sub;
  int my = tg % 10;
  int n0 = (tg / 10) * 128;
  int count = counts[e];
  int lane = tid & 63, wid = tid >> 6;
  int wm = wid >> 1, wn = wid & 1;
  int q = lane >> 4, lm = lane & 15;

  __shared__ __align__(16) char sm[3 * G1BUF];  // per buf: A 8KB @0, B 16KB @8K

  int rloc = tid >> 3;
  int chs = ((tid & 7) ^ (rloc & 7)) * 8;
  const u16* bP[4];
#pragma unroll
  for (int i = 0; i < 4; ++i)
    bP[i] = B + ((size_t)e * 2 * ID + n0 + rloc + 32 * i) * HD + chs;

#define STAGE1(base, kt)                                             \
  do {                                                               \
    int ko_ = (kt) * 64;                                             \
    char* sb_ = (base);                                              \
    async_cp16(aP[0] + ko_, sb_ + (0 * 256 + tid) * 16);             \
    async_cp16(aP[1] + ko_, sb_ + (1 * 256 + tid) * 16);             \
    async_cp16(bP[0] + ko_, sb_ + 8192 + (0 * 256 + tid) * 16);      \
    async_cp16(bP[1] + ko_, sb_ + 8192 + (1 * 256 + tid) * 16);      \
    async_cp16(bP[2] + ko_, sb_ + 8192 + (2 * 256 + tid) * 16);      \
    async_cp16(bP[3] + ko_, sb_ + 8192 + (3 * 256 + tid) * 16);      \
  } while (0)

  for (int m0 = my * 64; m0 < count; m0 += 640) {
    const u16* aP[2];
#pragma unroll
    for (int i = 0; i < 2; ++i) {
      int gr = m0 + rloc + 32 * i;
      int f = (gr < count) ? rowmap[e * CAP + gr] : 0;
      aP[i] = A + (size_t)(f >> 1) * HD + chs;
    }

    f32x4 zero = {0.f, 0.f, 0.f, 0.f};
    f32x4 acc[2][4];
#pragma unroll
    for (int mi = 0; mi < 2; ++mi)
#pragma unroll
      for (int ni = 0; ni < 4; ++ni) acc[mi][ni] = zero;

    STAGE1(sm, 0);
    STAGE1(sm + G1BUF, 1);
    int p = 0, pn2 = 2;
    for (int kt = 0; kt < HD / 64; ++kt) {
      if (kt == HD / 64 - 1)
        asm volatile("s_waitcnt vmcnt(0)\ns_barrier" ::: "memory");
      else
        asm volatile("s_waitcnt vmcnt(6)\ns_barrier" ::: "memory");
      const char* sb = sm + p * G1BUF;
      if (kt + 2 < HD / 64) STAGE1(sm + pn2 * G1BUF, kt + 2);
#pragma unroll
      for (int s = 0; s < 2; ++s) {
        int cs = ((s * 4 + q) ^ (lm & 7)) * 16;
        bf16x8 af[2], bfr[4];
#pragma unroll
        for (int mi = 0; mi < 2; ++mi)
          af[mi] = *(const bf16x8*)(sb + (wm * 32 + mi * 16 + lm) * 128 + cs);
#pragma unroll
        for (int ni = 0; ni < 4; ++ni)
          bfr[ni] = *(const bf16x8*)(sb + 8192 + (wn * 64 + ni * 16 + lm) * 128 + cs);
        __builtin_amdgcn_s_setprio(1);
#pragma unroll
        for (int mi = 0; mi < 2; ++mi)
#pragma unroll
          for (int ni = 0; ni < 4; ++ni)
            acc[mi][ni] = __builtin_amdgcn_mfma_f32_16x16x32_bf16(af[mi], bfr[ni], acc[mi][ni], 0, 0, 0);
        __builtin_amdgcn_s_setprio(0);
      }
      p = (p == 2) ? 0 : p + 1;
      pn2 = (pn2 == 2) ? 0 : pn2 + 1;
    }
    __syncthreads();  // full drain before LDS reuse by epilogue

    // ---- fused SiLU epilogue: merged 64x64 u16 tile ----
    u16* smOut = (u16*)sm;  // [64][72] u16
#pragma unroll
    for (int mi = 0; mi < 2; ++mi) {
#pragma unroll
      for (int k = 0; k < 2; ++k) {
        int colL = wn * 32 + k * 16 + lm;
#pragma unroll
        for (int r = 0; r < 4; ++r) {
          float g2 = acc[mi][2 * k][r];
          float u = acc[mi][2 * k + 1][r];
          float a = g2 / (1.f + __expf(-g2)) * u;
          int row = wm * 32 + mi * 16 + q * 4 + r;
          smOut[row * 72 + colL] = f2bf(a);
        }
      }
    }
    __syncthreads();
    {
      int row = tid >> 2, seg = tid & 3;
      const u16* sp = smOut + row * 72 + seg * 16;
      bf16x8 v0 = *(const bf16x8*)sp;
      bf16x8 v1 = *(const bf16x8*)(sp + 8);
      u16* dp = Hb + ((size_t)e * CAP + m0 + row) * ID + (n0 >> 1) + seg * 16;
      *(bf16x8*)dp = v0;
      *(bf16x8*)(dp + 8) = v1;
    }
    __syncthreads();  // smOut aliases staging buffers; fence before next m0
  }
}

// ---------------- GEMM2: 64x64, depth-2 counted-vmcnt pipeline ---------------
// Grid 1280 (e fastest -> same XCD affinity), y=10 + m0+=640 loop.
#define G2BUF 16384
__global__ __launch_bounds__(256) void gemm2_kernel(
    const u16* __restrict__ A, const u16* __restrict__ B, float* __restrict__ out,
    const int* __restrict__ rowmap, const int* __restrict__ counts,
    const float* __restrict__ tw) {
  int idx = blockIdx.x;
  int e = idx & 7;
  int tg = idx >> 3;
  int my = tg % 10;
  int n0 = (tg / 10) * 64;
  int count = counts[e];
  int tid = threadIdx.x;
  int lane = tid & 63, wid = tid >> 6;
  int wm = wid >> 1, wn = wid & 1;
  int q = lane >> 4, lm = lane & 15;

  __shared__ __align__(16) char sm[3 * G2BUF];  // per buf: A 8KB @0, B 8KB @8K

  int rloc = tid >> 3;
  int chs = ((tid & 7) ^ (rloc & 7)) * 8;
  const u16* bP[2];
#pragma unroll
  for (int i = 0; i < 2; ++i)
    bP[i] = B + ((size_t)e * HD + n0 + rloc + 32 * i) * ID + chs;

#define STAGE2(base, kt)                                             \
  do {                                                               \
    int ko_ = (kt) * 64;                                             \
    char* sb_ = (base);                                              \
    async_cp16(aP[0] + ko_, sb_ + (0 * 256 + tid) * 16);             \
    async_cp16(aP[1] + ko_, sb_ + (1 * 256 + tid) * 16);             \
    async_cp16(bP[0] + ko_, sb_ + 8192 + (0 * 256 + tid) * 16);      \
    async_cp16(bP[1] + ko_, sb_ + 8192 + (1 * 256 + tid) * 16);      \
  } while (0)

  for (int m0 = my * 64; m0 < count; m0 += 640) {
    const u16* aP[2];
#pragma unroll
    for (int i = 0; i < 2; ++i)
      aP[i] = A + ((size_t)e * CAP + m0 + rloc + 32 * i) * ID + chs;

    f32x4 zero = {0.f, 0.f, 0.f, 0.f};
    f32x4 acc[2][2];
#pragma unroll
    for (int mi = 0; mi < 2; ++mi)
#pragma unroll
      for (int ni = 0; ni < 2; ++ni) acc[mi][ni] = zero;

    STAGE2(sm, 0);
    STAGE2(sm + G2BUF, 1);
    int p = 0, pn2 = 2;
    for (int kt = 0; kt < ID / 64; ++kt) {
      if (kt == ID / 64 - 1)
        asm volatile("s_waitcnt vmcnt(0)\ns_barrier" ::: "memory");
      else
        asm volatile("s_waitcnt vmcnt(4)\ns_barrier" ::: "memory");
      const char* sb = sm + p * G2BUF;
      if (kt + 2 < ID / 64) STAGE2(sm + pn2 * G2BUF, kt + 2);
#pragma unroll
      for (int s = 0; s < 2; ++s) {
        int cs = ((s * 4 + q) ^ (lm & 7)) * 16;
        bf16x8 af[2], bfr[2];
#pragma unroll
        for (int mi = 0; mi < 2; ++mi)
          af[mi] = *(const bf16x8*)(sb + (wm * 32 + mi * 16 + lm) * 128 + cs);
#pragma unroll
        for (int ni = 0; ni < 2; ++ni)
          bfr[ni] = *(const bf16x8*)(sb + 8192 + (wn * 32 + ni * 16 + lm) * 128 + cs);
        __builtin_amdgcn_s_setprio(1);
#pragma unroll
        for (int mi = 0; mi < 2; ++mi)
#pragma unroll
          for (int ni = 0; ni < 2; ++ni)
            acc[mi][ni] = __builtin_amdgcn_mfma_f32_16x16x32_bf16(af[mi], bfr[ni], acc[mi][ni], 0, 0, 0);
        __builtin_amdgcn_s_setprio(0);
      }
      p = (p == 2) ? 0 : p + 1;
      pn2 = (pn2 == 2) ? 0 : pn2 + 1;
    }

    // fused combine epilogue: out[token, col] += w * y
#pragma unroll
    for (int mi = 0; mi < 2; ++mi) {
#pragma unroll
      for (int r = 0; r < 4; ++r) {
        int grow = m0 + wm * 32 + mi * 16 + q * 4 + r;
        if (grow < count) {
          int f = rowmap[e * CAP + grow];
          float w = tw[f];
          int t = f >> 1;
#pragma unroll
          for (int ni = 0; ni < 2; ++ni) {
            int col = n0 + wn * 32 + ni * 16 + lm;
            atomicAdd(&out[(size_t)t * HD + col], w * acc[mi][ni][r]);
          }
        }
      }
    }
    __syncthreads();  // sm safe before next m0 iteration's STAGE2
  }
}

extern "C" void kernel_launch(void* const* d_in, const int* in_sizes, int n_in,
                              void* d_out, int out_size, void* d_ws, size_t ws_size,
                              hipStream_t stream) {
  const float* hidden = (const float*)d_in[0];
  const float* w1 = (const float*)d_in[1];
  const float* w2 = (const float*)d_in[2];
  const float* tw = (const float*)d_in[3];
  const int* ids = (const int*)d_in[4];
  float* out = (float*)d_out;

  char* p = (char*)d_ws;
  auto alloc = [&](size_t b) { char* r = p; p += (b + 255) & ~(size_t)255; return r; };
  u16* bw1 = (u16*)alloc((size_t)NE * 2 * ID * HD * 2);   // 46.1 MB (interleaved)
  u16* bw2 = (u16*)alloc((size_t)NE * HD * ID * 2);        // 23.1 MB
  u16* bx = (u16*)alloc((size_t)TT * HD * 2);              // 4.2 MB
  u16* hbuf = (u16*)alloc((size_t)NE * CAP * ID * 2);      // 23.1 MB
  int* rowmap = (int*)alloc((size_t)NE * CAP * 4);
  int* counts = (int*)alloc((size_t)NE * 4);

  // prep: route (block 0) + w1 il-cvt + x cvt + out zero
  prep_kernel<<<1 + W1ROWS + XBLK + OZB, 256, 0, stream>>>(
      (const float4*)w1, (ushort4*)bw1, (const float4*)hidden, (ushort4*)bx,
      ids, rowmap, counts, (float4*)out);

  // GEMM1 + SiLU, w2-cvt riders interleaved 2-of-7 groups: 308 groups x 8
  gemm1_kernel<<<308 * 8, 256, 0, stream>>>(
      bx, bw1, hbuf, rowmap, counts, (const float4*)w2, (bf16x8*)bw2);

  // GEMM2 + combine: 8 experts x 10 m-groups x 16 n-tiles
  gemm2_kernel<<<8 * 10 * 16, 256, 0, stream>>>(
      hbuf, bw2, out, rowmap, counts, tw);
}